// Round 10
// baseline (3702.155 us; speedup 1.0000x reference)
//
#include <hip/hip_runtime.h>
#include <math.h>

// Problem dims
#define B_SZ   32
#define T_SZ   512
#define I_DIM  256
#define H_DIM  1024
#define P_DIM  512
#define G4     4096   // 4*H
#define O_DIM  256

// Workspace layout (bytes)
#define WS_RRBP      0            // 8 MB  RR packed B-fragments (bf16)
#define WS_WP_HI     8388608      // 1 MB
#define WS_WP_LO     9437184      // 1 MB
#define WS_RT_HI     10485760     // 4 MB  R^T planes [4096][512]
#define WS_RT_LO     14680064     // 4 MB
#define WS_WT_HI     18874368     // 2 MB  W^T planes [4096][256]
#define WS_WT_LO     20971520     // 2 MB
#define WS_IN_HI     23068672     // 8 MB  inputs planes row-major
#define WS_IN_LO     31457280     // 8 MB
#define WS_WPT       39845888     // 1 MB  W_proj^T bf16 [512][1024]
#define WS_LWB       40894464     // 256 KB lin_w bf16 [256][512]
#define WS_DONE      41943040     // 8 KB  consumer step flags
#define WS_PREADY    41951232     // 8 KB  producer chunk-ready
#define WS_CDONE     41959424     // 8 KB  consumer chunk-done
#define WS_HPK0      42991616     // 64 KB h fragment-packed ping
#define WS_HPK1      43057152     // 64 KB h fragment-packed pong
#define WS_HBF       44040192     // 32 MB h_seq bf16 [512][32][1024]
#define WS_XG0       77594624     // 32 MB xg chunk buffer 0 (f32)
#define WS_XG1       111149056    // 32 MB xg chunk buffer 1 (f32)
#define WS_HPBF      144703488    // 16 MB hp bf16 [16384][512]
#define WS_RRBUF     144703488    // 16 MB RR f32 (pre-persistent only; overlaps HPBF)

typedef short short8 __attribute__((ext_vector_type(8)));
typedef float f32x4  __attribute__((ext_vector_type(4)));
typedef unsigned long long u64;

__device__ __forceinline__ float sigmf(float x) { return 1.0f / (1.0f + __expf(-x)); }
__device__ __forceinline__ float tanhfast(float x) { return 1.0f - 2.0f / (__expf(2.0f * x) + 1.0f); }
__device__ __forceinline__ short f2bf(float f) {
    union { float f; unsigned u; } v; v.f = f;
    unsigned r = (v.u + 0x7FFF + ((v.u >> 16) & 1)) >> 16;
    return (short)r;
}
__device__ __forceinline__ float bf2f(short h) {
    union { unsigned u; float f; } v; v.u = ((unsigned)(unsigned short)h) << 16;
    return v.f;
}

// cache-bypass 16B load / 4B store (non-atomic -> fully pipelined, vmcnt-counted)
#define LDB(dst, base, off) \
    asm volatile("global_load_dwordx4 %0, %1, off offset:" off " sc0 sc1" \
                 : "=v"(dst) : "v"(base))
#define STB(addr, val) \
    asm volatile("global_store_dword %0, %1, off sc0 sc1" \
                 :: "v"(addr), "v"(val) : "memory")

// ---------------------------------------------------------------------------
__global__ void split_copy(const float* __restrict__ in, short* __restrict__ hi,
                           short* __restrict__ lo, int n)
{
    int i = blockIdx.x * 256 + threadIdx.x;
    if (i < n) {
        float v = in[i];
        short h = f2bf(v);
        hi[i] = h;
        if (lo) lo[i] = f2bf(v - bf2f(h));
    }
}

__global__ void transpose_split(const float* __restrict__ in, short* __restrict__ hi,
                                short* __restrict__ lo, int rows, int cols)
{
    __shared__ float t[32][33];
    int c0 = blockIdx.x * 32, r0 = blockIdx.y * 32;
    int x = threadIdx.x, y = threadIdx.y;   // 32 x 8
    #pragma unroll
    for (int i = y; i < 32; i += 8) t[i][x] = in[(size_t)(r0 + i) * cols + c0 + x];
    __syncthreads();
    #pragma unroll
    for (int i = y; i < 32; i += 8) {
        float v = t[x][i];
        short h = f2bf(v);
        size_t o = (size_t)(c0 + i) * rows + r0 + x;
        hi[o] = h;
        if (lo) lo[o] = f2bf(v - bf2f(h));
    }
}

// ---------------------------------------------------------------------------
// MFMA bf16 GEMM tile body (one 128x128 C tile at m0,n0). Same as rounds 4-9.
// ---------------------------------------------------------------------------
template<int SPLIT, int AMODE, int CMODE, int BIAS>
__device__ __forceinline__
void gemm_tile(const short* __restrict__ Ah, const short* __restrict__ Al,
               const short* __restrict__ Bh, const short* __restrict__ Bl,
               const float* __restrict__ bias, void* __restrict__ Cp,
               int N, int K, int t0, int m0, int n0)
{
    __shared__ short As[SPLIT + 1][8192];   // [plane][row*64 + k], 16KB each
    __shared__ short Bs[SPLIT + 1][8192];
    const int tid = threadIdx.x;
    const int l   = tid & 63;
    const int w   = tid >> 6;
    const int wm  = w & 1, wn = w >> 1;

    f32x4 acc[4][4] = {};

    for (int k0 = 0; k0 < K; k0 += 64) {
        __syncthreads();
        #pragma unroll
        for (int q = 0; q < 4; q++) {
            int rg   = q * 4 + w;
            int rr   = (rg << 3) + (l >> 3);
            int slot = (l & 7) ^ (rr & 7);        // pre-swizzled source slot
            int lidx = rg * 512 + l * 8;          // linear LDS dest (shorts)
            size_t aoff, boff;
            int ra = m0 + rr, rb = n0 + rr;
            if constexpr (AMODE == 1)
                aoff = (size_t)((ra & 31) * 512 + t0 + (ra >> 5)) * 256 + k0 + slot * 8;
            else
                aoff = (size_t)ra * K + k0 + slot * 8;
            boff = (size_t)rb * K + k0 + slot * 8;
            __builtin_amdgcn_global_load_lds(Ah + aoff, &As[0][lidx], 16, 0, 0);
            __builtin_amdgcn_global_load_lds(Bh + boff, &Bs[0][lidx], 16, 0, 0);
            if constexpr (SPLIT) {
                __builtin_amdgcn_global_load_lds(Al + aoff, &As[1][lidx], 16, 0, 0);
                __builtin_amdgcn_global_load_lds(Bl + boff, &Bs[1][lidx], 16, 0, 0);
            }
        }
        __syncthreads();

        #pragma unroll
        for (int ks = 0; ks < 2; ks++) {
            const int cb = (((ks * 4) + (l >> 4)) ^ (l & 7)) * 16;  // swizzled col byte
            short8 af[4], bfr[4], afl[4], bfl[4];
            #pragma unroll
            for (int mf = 0; mf < 4; mf++) {
                int mloc = wm * 64 + mf * 16 + (l & 15);
                af[mf] = *(const short8*)((const char*)As[0] + mloc * 128 + cb);
                if constexpr (SPLIT)
                    afl[mf] = *(const short8*)((const char*)As[1] + mloc * 128 + cb);
            }
            #pragma unroll
            for (int nf = 0; nf < 4; nf++) {
                int nloc = wn * 64 + nf * 16 + (l & 15);
                bfr[nf] = *(const short8*)((const char*)Bs[0] + nloc * 128 + cb);
                if constexpr (SPLIT)
                    bfl[nf] = *(const short8*)((const char*)Bs[1] + nloc * 128 + cb);
            }
            #pragma unroll
            for (int mf = 0; mf < 4; mf++)
                #pragma unroll
                for (int nf = 0; nf < 4; nf++)
                    acc[mf][nf] = __builtin_amdgcn_mfma_f32_16x16x32_bf16(
                        af[mf], bfr[nf], acc[mf][nf], 0, 0, 0);
            if constexpr (SPLIT) {
                #pragma unroll
                for (int mf = 0; mf < 4; mf++)
                    #pragma unroll
                    for (int nf = 0; nf < 4; nf++)
                        acc[mf][nf] = __builtin_amdgcn_mfma_f32_16x16x32_bf16(
                            af[mf], bfl[nf], acc[mf][nf], 0, 0, 0);
                #pragma unroll
                for (int mf = 0; mf < 4; mf++)
                    #pragma unroll
                    for (int nf = 0; nf < 4; nf++)
                        acc[mf][nf] = __builtin_amdgcn_mfma_f32_16x16x32_bf16(
                            afl[mf], bfr[nf], acc[mf][nf], 0, 0, 0);
            }
        }
    }

    float bv[4];
    if constexpr (BIAS) {
        #pragma unroll
        for (int nf = 0; nf < 4; nf++)
            bv[nf] = bias[n0 + wn * 64 + nf * 16 + (l & 15)];
    }
    #pragma unroll
    for (int mf = 0; mf < 4; mf++) {
        #pragma unroll
        for (int r = 0; r < 4; r++) {
            int row = m0 + wm * 64 + mf * 16 + (l >> 4) * 4 + r;
            #pragma unroll
            for (int nf = 0; nf < 4; nf++) {
                int col = n0 + wn * 64 + nf * 16 + (l & 15);
                float v = acc[mf][nf][r];
                if constexpr (BIAS) v += bv[nf];
                if constexpr (CMODE == 0)
                    ((float*)Cp)[(size_t)row * N + col] = v;
                else if constexpr (CMODE == 1)
                    ((short*)Cp)[(size_t)row * N + col] = f2bf(v);
                else
                    ((float*)Cp)[(size_t)(row & 31) * (T_SZ * O_DIM)
                                 + (size_t)(row >> 5) * O_DIM + col] = v;
            }
        }
    }
}

// ---- concrete (non-template) kernel entry points ----
__global__ __launch_bounds__(256)
void gemm_rr(const short* Ah, const short* Al, const short* Bh, const short* Bl,
             const float* bias, void* Cp, int N, int K, int t0)
{ gemm_tile<1, 0, 0, 0>(Ah, Al, Bh, Bl, bias, Cp, N, K, t0, blockIdx.y * 128, blockIdx.x * 128); }

__global__ __launch_bounds__(256)
void gemm_proj(const short* Ah, const short* Al, const short* Bh, const short* Bl,
               const float* bias, void* Cp, int N, int K, int t0)
{ gemm_tile<0, 0, 1, 0>(Ah, Al, Bh, Bl, bias, Cp, N, K, t0, blockIdx.y * 128, blockIdx.x * 128); }

__global__ __launch_bounds__(256)
void gemm_out(const short* Ah, const short* Al, const short* Bh, const short* Bl,
              const float* bias, void* Cp, int N, int K, int t0)
{ gemm_tile<0, 0, 2, 1>(Ah, Al, Bh, Bl, bias, Cp, N, K, t0, blockIdx.y * 128, blockIdx.x * 128); }

// ---------------------------------------------------------------------------
// Pack RR into per-block MFMA B-fragment order (128 blocks x 8 j-cols):
// RRbp[blk 128][wn 2][kt 32][lane 64][i 8]; nl=wn*16+(lane&15), g=nl>>3,
// jl=nl&7, col=g*1024+blk*8+jl; k = kt*32+(lane>>4)*8+i  (same k-slot
// formula as the hout A-pack, so k-permutation ambiguity cancels).
// ---------------------------------------------------------------------------
__global__ __launch_bounds__(256)
void pack_rr(const float* __restrict__ RRf, short* __restrict__ RRbp)
{
    int idx = blockIdx.x * 256 + threadIdx.x;     // short8 slot, 0..524287
    int lane = idx & 63;
    int kt   = (idx >> 6) & 31;
    int wn   = (idx >> 11) & 1;
    int blk  = idx >> 12;
    int nl = wn * 16 + (lane & 15);
    int g = nl >> 3, jl = nl & 7;
    int col = g * 1024 + blk * 8 + jl;
    int kbase = kt * 32 + (lane >> 4) * 8;
    short8 v;
    #pragma unroll
    for (int i = 0; i < 8; i++)
        v[i] = f2bf(RRf[(size_t)(kbase + i) * G4 + col]);
    ((short8*)RRbp)[idx] = v;
}

// ---------------------------------------------------------------------------
__device__ __forceinline__ void waitall(int* slots, int tid, int target, bool fence)
{
    if (tid < 64) {
        const int i0 = (tid * 2) * 16, i1 = (tid * 2 + 1) * 16;
        for (;;) {
            int v0 = __hip_atomic_load(&slots[i0], __ATOMIC_RELAXED, __HIP_MEMORY_SCOPE_AGENT);
            int v1 = __hip_atomic_load(&slots[i1], __ATOMIC_RELAXED, __HIP_MEMORY_SCOPE_AGENT);
            if (__all(v0 >= target && v1 >= target)) break;
            __builtin_amdgcn_s_sleep(1);
        }
        if (fence) __threadfence();   // heavy acquire: only at chunk handoff
    }
    __syncthreads();
}

// Light step barrier among the 128 consumer blocks (R6-proven). The leading
// __syncthreads drains vmcnt so all bypass stores are at the LLC first.
__device__ __forceinline__ void gridbar_light(int* done, int bid, int tid, int target)
{
    __syncthreads();
    if (tid == 0)
        __hip_atomic_store(&done[bid * 16], target,
                           __ATOMIC_RELEASE, __HIP_MEMORY_SCOPE_AGENT);
    if (tid < 64) {
        const int i0 = (tid * 2) * 16, i1 = (tid * 2 + 1) * 16;
        for (;;) {
            int v0 = __hip_atomic_load(&done[i0], __ATOMIC_RELAXED, __HIP_MEMORY_SCOPE_AGENT);
            int v1 = __hip_atomic_load(&done[i1], __ATOMIC_RELAXED, __HIP_MEMORY_SCOPE_AGENT);
            if (__all(v0 >= target && v1 >= target)) break;
            __builtin_amdgcn_s_sleep(1);
        }
    }
    __syncthreads();
}

// ---------------------------------------------------------------------------
// Persistent kernel, 256 blocks x 256 threads (1 block/CU).
// Blocks 128..255: producers — xg chunks into xg0/xg1 (double buffer).
// Blocks 0..127: consumers — R6 structure, but: B slice resident in LDS
// (loaded once, immune to chunk fences), A(h) loads via PIPELINED asm
// sc0/sc1 bypass loads (not serialized atomics), c in registers, xg
// prefetched before the MFMA chain, h stored via asm bypass stores.
// ---------------------------------------------------------------------------
__global__ __launch_bounds__(256, 1)
void lstm_persistent(const short* __restrict__ in_hi, const short* __restrict__ in_lo,
                     const short* __restrict__ Wt_hi, const short* __restrict__ Wt_lo,
                     const float* __restrict__ bvec,
                     const short* __restrict__ RRbp,
                     float* __restrict__ xg0, float* __restrict__ xg1,
                     short* __restrict__ hpk0, short* __restrict__ hpk1,
                     short* __restrict__ h_bf,
                     const float* __restrict__ p,
                     int* __restrict__ done, int* __restrict__ pready,
                     int* __restrict__ cdone)
{
    const int tid = threadIdx.x;
    const int bid = blockIdx.x;

    if (bid >= 128) {
        // ---------------- producers ----------------
        const int pb = bid - 128;
        for (int chunk = 0; chunk < 8; chunk++) {
            if (chunk >= 2) waitall(cdone, tid, chunk - 1, false);  // buf free?
            float* xgc = (chunk & 1) ? xg1 : xg0;
            #pragma unroll 1
            for (int q = 0; q < 4; q++) {
                int ti = pb * 4 + q;                   // 0..511 tiles (16m x 32n)
                gemm_tile<1, 1, 0, 1>(in_hi, in_lo, Wt_hi, Wt_lo, bvec, xgc,
                                      G4, I_DIM, chunk * 64,
                                      (ti >> 5) * 128, (ti & 31) * 128);
            }
            __syncthreads();
            if (tid == 0)   // agent release: L2 writeback so xg is visible
                __hip_atomic_store(&pready[pb * 16], chunk + 1,
                                   __ATOMIC_RELEASE, __HIP_MEMORY_SCOPE_AGENT);
        }
        return;
    }

    // ---------------- consumers: recurrence ----------------
    __shared__ short Bl_lds[2][32][512];   // 64KB: [wn][kt][lane*8] B-fragments
    __shared__ float zbuf[32][33];
    const int lane = tid & 63;
    const int w    = tid >> 6;
    const int wm   = w & 1;               // batch half
    const int wn   = w >> 1;              // gate-col half
    const int eb = tid >> 3, ejl = tid & 7, ej = bid * 8 + ejl;
    float cv = 0.0f;                      // cell state in register
    const float pi = p[ej], pf = p[1024 + ej], po = p[2048 + ej];

    // one-time: B slice (64KB) global -> LDS (normal cached loads, then fenced off)
    {
        const u64* src = (const u64*)RRbp + (size_t)bid * 8192;
        u64* dst = (u64*)&Bl_lds[0][0][0];
        #pragma unroll 4
        for (int i = tid; i < 8192; i += 256) dst[i] = src[i];
        __syncthreads();
    }

    const int lane2 = (eb & 15) | (((ej & 31) >> 3) << 4);
    const int kt2   = ej >> 5;
    const int wm2   = eb >> 4;
    const size_t sidx = ((size_t)((wm2 * 32 + kt2) * 64 + lane2)) * 8 + ejl;

    for (int chunk = 0; chunk < 8; chunk++) {
        waitall(pready, tid, chunk + 1, true);   // heavy acquire (once/chunk)
        const float* xgc = (chunk & 1) ? xg1 : xg0;

        for (int tl = 0; tl < 64; tl++) {
            const int t = chunk * 64 + tl;
            const short* hin = (t & 1) ? hpk1 : hpk0;
            short*      hout = (t & 1) ? hpk0 : hpk1;
            const float* xg_t = xgc + (size_t)tl * (B_SZ * G4);

            // prefetch xg gate values (normal loads; arrive under the A-loads)
            const float* xr = xg_t + (size_t)eb * G4 + ej;
            float xzi = xr[0], xzf = xr[1024], xzg = xr[2048], xzo = xr[3072];

            // issue all 32 A(h) bypass loads, fully pipelined
            short8 a[32];
            const char* Ab = (const char*)hin + (((size_t)(wm * 32) * 64 + lane) * 16);
            #define ISSUE4(i, bp) LDB(a[(i)], bp, "0"); LDB(a[(i)+1], bp, "1024"); \
                                  LDB(a[(i)+2], bp, "2048"); LDB(a[(i)+3], bp, "3072");
            ISSUE4(0,  Ab);          ISSUE4(4,  Ab + 4096);
            ISSUE4(8,  Ab + 8192);   ISSUE4(12, Ab + 12288);
            ISSUE4(16, Ab + 16384);  ISSUE4(20, Ab + 20480);
            ISSUE4(24, Ab + 24576);  ISSUE4(28, Ab + 28672);
            #undef ISSUE4
            asm volatile("s_waitcnt vmcnt(0)" ::: "memory");
            __builtin_amdgcn_sched_barrier(0);

            f32x4 acc0 = {0.f, 0.f, 0.f, 0.f};
            f32x4 acc1 = {0.f, 0.f, 0.f, 0.f};
            #pragma unroll
            for (int i = 0; i < 16; i++) {
                short8 bv = *(const short8*)&Bl_lds[wn][i][lane * 8];
                acc0 = __builtin_amdgcn_mfma_f32_16x16x32_bf16(a[i], bv, acc0, 0, 0, 0);
            }
            #pragma unroll
            for (int i = 16; i < 32; i++) {
                short8 bv = *(const short8*)&Bl_lds[wn][i][lane * 8];
                acc1 = __builtin_amdgcn_mfma_f32_16x16x32_bf16(a[i], bv, acc1, 0, 0, 0);
            }
            acc0[0] += acc1[0]; acc0[1] += acc1[1];
            acc0[2] += acc1[2]; acc0[3] += acc1[3];

            {   // C/D layout: col=lane&15, row=(lane>>4)*4+r
                int col = lane & 15;
                int row = (lane >> 4) * 4;
                #pragma unroll
                for (int r = 0; r < 4; r++)
                    zbuf[wm * 16 + row + r][wn * 16 + col] = acc0[r];
            }
            __syncthreads();

            {   // gate epilogue: thread (eb, ejl); c in register
                float zi = zbuf[eb][ejl]      + xzi;
                float zf = zbuf[eb][8 + ejl]  + xzf;
                float zg = zbuf[eb][16 + ejl] + xzg;
                float zo = zbuf[eb][24 + ejl] + xzo;
                float ig = sigmf(zi + cv * pi);
                float fg = sigmf(zf + cv * pf);
                float gg = tanhfast(zg);
                float cn = fg * cv + ig * gg;
                float og = sigmf(zo + cn * po);
                float hv = og * tanhfast(cn);
                cv = cn;
                unsigned hb = (unsigned)(unsigned short)f2bf(hv);
                unsigned other = __shfl_xor(hb, 1);
                if ((tid & 1) == 0) {
                    unsigned pk = hb | (other << 16);
                    unsigned* ha = (unsigned*)hout + (sidx >> 1);
                    STB(ha, pk);     // bypass store -> visible to all XCDs
                    size_t hidx = (size_t)t * (B_SZ * H_DIM) + (size_t)eb * H_DIM + ej;
                    *((unsigned*)h_bf + (hidx >> 1)) = pk;   // normal (post-kernel use)
                }
            }
            gridbar_light(done, bid, tid, t + 1);
        }
        if (tid == 0)
            __hip_atomic_store(&cdone[bid * 16], chunk + 1,
                               __ATOMIC_RELAXED, __HIP_MEMORY_SCOPE_AGENT);
    }
}

// ---------------------------------------------------------------------------
extern "C" void kernel_launch(void* const* d_in, const int* in_sizes, int n_in,
                              void* d_out, int out_size, void* d_ws, size_t ws_size,
                              hipStream_t stream)
{
    const float* inp    = (const float*)d_in[0];  // (32,512,256)
    const float* W      = (const float*)d_in[1];  // (256,4096)
    const float* R      = (const float*)d_in[2];  // (512,4096)
    const float* W_proj = (const float*)d_in[3];  // (1024,512)
    const float* p      = (const float*)d_in[4];  // (3072,)
    const float* bvec   = (const float*)d_in[5];  // (4096,)
    const float* lin_w  = (const float*)d_in[6];  // (256,512)
    const float* lin_b  = (const float*)d_in[7];  // (256,)
    float* out = (float*)d_out;
    char* ws = (char*)d_ws;

    short* RRbp  = (short*)(ws + WS_RRBP);
    short* Wp_hi = (short*)(ws + WS_WP_HI);
    short* Wp_lo = (short*)(ws + WS_WP_LO);
    short* Rt_hi = (short*)(ws + WS_RT_HI);
    short* Rt_lo = (short*)(ws + WS_RT_LO);
    short* Wt_hi = (short*)(ws + WS_WT_HI);
    short* Wt_lo = (short*)(ws + WS_WT_LO);
    short* in_hi = (short*)(ws + WS_IN_HI);
    short* in_lo = (short*)(ws + WS_IN_LO);
    short* Wpt   = (short*)(ws + WS_WPT);
    short* lwb   = (short*)(ws + WS_LWB);
    int*   done  = (int*)(ws + WS_DONE);
    int*   pready= (int*)(ws + WS_PREADY);
    int*   cdone = (int*)(ws + WS_CDONE);
    short* hpk0  = (short*)(ws + WS_HPK0);
    short* hpk1  = (short*)(ws + WS_HPK1);
    short* h_bf  = (short*)(ws + WS_HBF);
    float* xg0   = (float*)(ws + WS_XG0);
    float* xg1   = (float*)(ws + WS_XG1);
    short* hp_bf = (short*)(ws + WS_HPBF);
    float* RRbuf = (float*)(ws + WS_RRBUF);   // dead before persistent kernel

    hipMemsetAsync(hpk0, 0, 65536, stream);
    hipMemsetAsync(done, 0, 24576, stream);   // done + pready + cdone (contiguous)

    // ---- prepack weights/inputs into bf16 (hi/lo) planes ----
    split_copy<<<(H_DIM * P_DIM + 255) / 256, 256, 0, stream>>>(W_proj, Wp_hi, Wp_lo, H_DIM * P_DIM);
    split_copy<<<(B_SZ * T_SZ * I_DIM + 255) / 256, 256, 0, stream>>>(inp, in_hi, in_lo, B_SZ * T_SZ * I_DIM);
    split_copy<<<(O_DIM * P_DIM + 255) / 256, 256, 0, stream>>>(lin_w, lwb, nullptr, O_DIM * P_DIM);
    transpose_split<<<dim3(G4 / 32, P_DIM / 32), dim3(32, 8), 0, stream>>>(R, Rt_hi, Rt_lo, P_DIM, G4);
    transpose_split<<<dim3(G4 / 32, I_DIM / 32), dim3(32, 8), 0, stream>>>(W, Wt_hi, Wt_lo, I_DIM, G4);
    transpose_split<<<dim3(P_DIM / 32, H_DIM / 32), dim3(32, 8), 0, stream>>>(W_proj, Wpt, nullptr, H_DIM, P_DIM);

    // ---- RR = W_proj @ R (split, ~f32 precision), pack to B-fragments ----
    gemm_rr<<<dim3(G4 / 128, H_DIM / 128), 256, 0, stream>>>(
        Wp_hi, Wp_lo, Rt_hi, Rt_lo, nullptr, RRbuf, G4, P_DIM, 0);
    pack_rr<<<2048, 256, 0, stream>>>(RRbuf, RRbp);

    // ---- persistent producer/consumer recurrence (one kernel) ----
    lstm_persistent<<<256, 256, 0, stream>>>(
        in_hi, in_lo, Wt_hi, Wt_lo, bvec, RRbp, xg0, xg1,
        hpk0, hpk1, h_bf, p, done, pready, cdone);

    // ---- hp = h @ W_proj (single-pass bf16, bf16 output) ----
    gemm_proj<<<dim3(P_DIM / 128, 16384 / 128), 256, 0, stream>>>(
        h_bf, nullptr, Wpt, nullptr, nullptr, hp_bf, P_DIM, H_DIM, 0);

    // ---- out = hp @ lin_w^T + lin_b (single-pass bf16, f32 remapped out) ----
    gemm_out<<<dim3(O_DIM / 128, 16384 / 128), 256, 0, stream>>>(
        hp_bf, nullptr, lwb, nullptr, lin_b, out, O_DIM, P_DIM, 0);
}

// Round 11
// 2363.510 us; speedup vs baseline: 1.5664x; 1.5664x over previous
//
#include <hip/hip_runtime.h>
#include <math.h>

// Problem dims
#define B_SZ   32
#define T_SZ   512
#define I_DIM  256
#define H_DIM  1024
#define P_DIM  512
#define G4     4096   // 4*H
#define O_DIM  256

typedef short short8 __attribute__((ext_vector_type(8)));
typedef float f32x4  __attribute__((ext_vector_type(4)));

__device__ __forceinline__ float sigmf(float x) { return 1.0f / (1.0f + __expf(-x)); }
__device__ __forceinline__ float tanhfast(float x) { return 1.0f - 2.0f / (__expf(2.0f * x) + 1.0f); }
__device__ __forceinline__ short f2bf(float f) {
    union { float f; unsigned u; } v; v.f = f;
    unsigned r = (v.u + 0x7FFF + ((v.u >> 16) & 1)) >> 16;
    return (short)r;
}
__device__ __forceinline__ float bf2f(short h) {
    union { unsigned u; float f; } v; v.u = ((unsigned)(unsigned short)h) << 16;
    return v.f;
}

// ---------------------------------------------------------------------------
__global__ void split_copy(const float* __restrict__ in, short* __restrict__ hi,
                           short* __restrict__ lo, int n)
{
    int i = blockIdx.x * 256 + threadIdx.x;
    if (i < n) {
        float v = in[i];
        short h = f2bf(v);
        hi[i] = h;
        if (lo) lo[i] = f2bf(v - bf2f(h));
    }
}

__global__ void transpose_split(const float* __restrict__ in, short* __restrict__ hi,
                                short* __restrict__ lo, int rows, int cols)
{
    __shared__ float t[32][33];
    int c0 = blockIdx.x * 32, r0 = blockIdx.y * 32;
    int x = threadIdx.x, y = threadIdx.y;   // 32 x 8
    #pragma unroll
    for (int i = y; i < 32; i += 8) t[i][x] = in[(size_t)(r0 + i) * cols + c0 + x];
    __syncthreads();
    #pragma unroll
    for (int i = y; i < 32; i += 8) {
        float v = t[x][i];
        short h = f2bf(v);
        size_t o = (size_t)(c0 + i) * rows + r0 + x;
        hi[o] = h;
        if (lo) lo[o] = f2bf(v - bf2f(h));
    }
}

// ---------------------------------------------------------------------------
// MFMA bf16 GEMM tile body (one 128x128 C tile at m0,n0). Same as rounds 4-10.
// ---------------------------------------------------------------------------
template<int SPLIT, int AMODE, int CMODE, int BIAS>
__device__ __forceinline__
void gemm_tile(const short* __restrict__ Ah, const short* __restrict__ Al,
               const short* __restrict__ Bh, const short* __restrict__ Bl,
               const float* __restrict__ bias, void* __restrict__ Cp,
               int N, int K, int t0, int m0, int n0)
{
    __shared__ short As[SPLIT + 1][8192];   // [plane][row*64 + k], 16KB each
    __shared__ short Bs[SPLIT + 1][8192];
    const int tid = threadIdx.x;
    const int l   = tid & 63;
    const int w   = tid >> 6;
    const int wm  = w & 1, wn = w >> 1;

    f32x4 acc[4][4] = {};

    for (int k0 = 0; k0 < K; k0 += 64) {
        __syncthreads();
        #pragma unroll
        for (int q = 0; q < 4; q++) {
            int rg   = q * 4 + w;
            int rr   = (rg << 3) + (l >> 3);
            int slot = (l & 7) ^ (rr & 7);        // pre-swizzled source slot
            int lidx = rg * 512 + l * 8;          // linear LDS dest (shorts)
            size_t aoff, boff;
            int ra = m0 + rr, rb = n0 + rr;
            if constexpr (AMODE == 1)
                aoff = (size_t)((ra & 31) * 512 + t0 + (ra >> 5)) * 256 + k0 + slot * 8;
            else
                aoff = (size_t)ra * K + k0 + slot * 8;
            boff = (size_t)rb * K + k0 + slot * 8;
            __builtin_amdgcn_global_load_lds(Ah + aoff, &As[0][lidx], 16, 0, 0);
            __builtin_amdgcn_global_load_lds(Bh + boff, &Bs[0][lidx], 16, 0, 0);
            if constexpr (SPLIT) {
                __builtin_amdgcn_global_load_lds(Al + aoff, &As[1][lidx], 16, 0, 0);
                __builtin_amdgcn_global_load_lds(Bl + boff, &Bs[1][lidx], 16, 0, 0);
            }
        }
        __syncthreads();

        #pragma unroll
        for (int ks = 0; ks < 2; ks++) {
            const int cb = (((ks * 4) + (l >> 4)) ^ (l & 7)) * 16;  // swizzled col byte
            short8 af[4], bfr[4], afl[4], bfl[4];
            #pragma unroll
            for (int mf = 0; mf < 4; mf++) {
                int mloc = wm * 64 + mf * 16 + (l & 15);
                af[mf] = *(const short8*)((const char*)As[0] + mloc * 128 + cb);
                if constexpr (SPLIT)
                    afl[mf] = *(const short8*)((const char*)As[1] + mloc * 128 + cb);
            }
            #pragma unroll
            for (int nf = 0; nf < 4; nf++) {
                int nloc = wn * 64 + nf * 16 + (l & 15);
                bfr[nf] = *(const short8*)((const char*)Bs[0] + nloc * 128 + cb);
                if constexpr (SPLIT)
                    bfl[nf] = *(const short8*)((const char*)Bs[1] + nloc * 128 + cb);
            }
            #pragma unroll
            for (int mf = 0; mf < 4; mf++)
                #pragma unroll
                for (int nf = 0; nf < 4; nf++)
                    acc[mf][nf] = __builtin_amdgcn_mfma_f32_16x16x32_bf16(
                        af[mf], bfr[nf], acc[mf][nf], 0, 0, 0);
            if constexpr (SPLIT) {
                #pragma unroll
                for (int mf = 0; mf < 4; mf++)
                    #pragma unroll
                    for (int nf = 0; nf < 4; nf++)
                        acc[mf][nf] = __builtin_amdgcn_mfma_f32_16x16x32_bf16(
                            af[mf], bfl[nf], acc[mf][nf], 0, 0, 0);
                #pragma unroll
                for (int mf = 0; mf < 4; mf++)
                    #pragma unroll
                    for (int nf = 0; nf < 4; nf++)
                        acc[mf][nf] = __builtin_amdgcn_mfma_f32_16x16x32_bf16(
                            afl[mf], bfr[nf], acc[mf][nf], 0, 0, 0);
            }
        }
    }

    float bv[4];
    if constexpr (BIAS) {
        #pragma unroll
        for (int nf = 0; nf < 4; nf++)
            bv[nf] = bias[n0 + wn * 64 + nf * 16 + (l & 15)];
    }
    #pragma unroll
    for (int mf = 0; mf < 4; mf++) {
        #pragma unroll
        for (int r = 0; r < 4; r++) {
            int row = m0 + wm * 64 + mf * 16 + (l >> 4) * 4 + r;
            #pragma unroll
            for (int nf = 0; nf < 4; nf++) {
                int col = n0 + wn * 64 + nf * 16 + (l & 15);
                float v = acc[mf][nf][r];
                if constexpr (BIAS) v += bv[nf];
                if constexpr (CMODE == 0)
                    ((float*)Cp)[(size_t)row * N + col] = v;
                else if constexpr (CMODE == 1)
                    ((short*)Cp)[(size_t)row * N + col] = f2bf(v);
                else
                    ((float*)Cp)[(size_t)(row & 31) * (T_SZ * O_DIM)
                                 + (size_t)(row >> 5) * O_DIM + col] = v;
            }
        }
    }
}

// ---- concrete (non-template) kernel entry points ----
__global__ __launch_bounds__(256)
void gemm_rr(const short* Ah, const short* Al, const short* Bh, const short* Bl,
             const float* bias, void* Cp, int N, int K, int t0)
{ gemm_tile<1, 0, 0, 0>(Ah, Al, Bh, Bl, bias, Cp, N, K, t0, blockIdx.y * 128, blockIdx.x * 128); }

// xg: SINGLE-PASS bf16 (was split-3). Added noise < existing bf16-h noise.
__global__ __launch_bounds__(256)
void gemm_xg(const short* Ah, const short* Al, const short* Bh, const short* Bl,
             const float* bias, void* Cp, int N, int K, int t0)
{ gemm_tile<0, 1, 0, 1>(Ah, Al, Bh, Bl, bias, Cp, N, K, t0, blockIdx.y * 128, blockIdx.x * 128); }

__global__ __launch_bounds__(256)
void gemm_proj(const short* Ah, const short* Al, const short* Bh, const short* Bl,
               const float* bias, void* Cp, int N, int K, int t0)
{ gemm_tile<0, 0, 1, 0>(Ah, Al, Bh, Bl, bias, Cp, N, K, t0, blockIdx.y * 128, blockIdx.x * 128); }

__global__ __launch_bounds__(256)
void gemm_out(const short* Ah, const short* Al, const short* Bh, const short* Bl,
              const float* bias, void* Cp, int N, int K, int t0)
{ gemm_tile<0, 0, 2, 1>(Ah, Al, Bh, Bl, bias, Cp, N, K, t0, blockIdx.y * 128, blockIdx.x * 128); }

// ---------------------------------------------------------------------------
// Pack RR (f32 [1024 k][4096 gatecol]) into per-block MFMA B-fragment order
// for 256 step-blocks of 16 gatecols (4 j x 4 gates):
// RRbp[blk 256][kt 32][lane 64][i 8]; nl=lane&15 -> g=nl>>2, jl=nl&3,
// col = g*1024 + blk*4 + jl; k = kt*32 + (lane>>4)*8 + i  (same k-slot
// formula as the hout A-pack, so k-permutation ambiguity cancels).
// ---------------------------------------------------------------------------
__global__ __launch_bounds__(256)
void pack_rr(const float* __restrict__ RRf, short* __restrict__ RRbp)
{
    int idx = blockIdx.x * 256 + threadIdx.x;     // short8 slot, 0..524287
    int lane = idx & 63;
    int kt   = (idx >> 6) & 31;
    int blk  = idx >> 11;
    int nl = lane & 15;
    int g = nl >> 2, jl = nl & 3;
    int col = g * 1024 + blk * 4 + jl;
    int kbase = kt * 32 + (lane >> 4) * 8;
    short8 v;
    #pragma unroll
    for (int i = 0; i < 8; i++)
        v[i] = f2bf(RRf[(size_t)(kbase + i) * G4 + col]);
    ((short8*)RRbp)[idx] = v;
}

// ---------------------------------------------------------------------------
// One LSTM step via MFMA. Grid: 256 blocks (4 j-cols each), 256 threads.
// 4 waves = (wm batch-half) x (kh K-half); per wave 16 MFMA + 32x16B loads.
// xg gate values PREFETCHED at kernel entry (latency hides under A-loads
// + MFMA chain instead of serializing after the zbuf sync).
// ---------------------------------------------------------------------------
__global__ __launch_bounds__(256)
void lstm_step(const float* __restrict__ xg_t,
               const short* __restrict__ RRbp,
               const short* __restrict__ hp_in,
               short* __restrict__ hp_out,
               short* __restrict__ h_bf_t,
               float* __restrict__ c_st,
               const float* __restrict__ p)
{
    __shared__ float zbuf[2][32][17];
    const int tid  = threadIdx.x;
    const int bid  = blockIdx.x;          // j0 = bid*4
    const int lane = tid & 63;
    const int w    = tid >> 6;
    const int wm   = w & 1;               // batch half
    const int kh   = w >> 1;              // K half

    // ---- epilogue-role prefetch (xg + c), issued before the MFMA chain ----
    const int eb = tid >> 2, ejl = tid & 3;       // valid when tid < 128
    const int ej = bid * 4 + ejl;
    float xzi = 0.f, xzf = 0.f, xzg = 0.f, xzo = 0.f, cv = 0.f;
    if (tid < 128) {
        const float* xr = xg_t + (size_t)eb * G4 + ej;
        xzi = xr[0]; xzf = xr[1024]; xzg = xr[2048]; xzo = xr[3072];
        cv = c_st[eb * H_DIM + ej];
    }

    const short8* Ap = (const short8*)hp_in + (size_t)(wm * 32 + kh * 16) * 64 + lane;
    const short8* Bp = (const short8*)RRbp + (size_t)(bid * 32 + kh * 16) * 64 + lane;

    f32x4 acc0 = {0.f, 0.f, 0.f, 0.f};
    f32x4 acc1 = {0.f, 0.f, 0.f, 0.f};
    #pragma unroll
    for (int i = 0; i < 8; i++) {
        short8 a = Ap[(size_t)i * 64];
        short8 b = Bp[(size_t)i * 64];
        acc0 = __builtin_amdgcn_mfma_f32_16x16x32_bf16(a, b, acc0, 0, 0, 0);
    }
    #pragma unroll
    for (int i = 8; i < 16; i++) {
        short8 a = Ap[(size_t)i * 64];
        short8 b = Bp[(size_t)i * 64];
        acc1 = __builtin_amdgcn_mfma_f32_16x16x32_bf16(a, b, acc1, 0, 0, 0);
    }
    acc0[0] += acc1[0]; acc0[1] += acc1[1]; acc0[2] += acc1[2]; acc0[3] += acc1[3];

    {   // C/D layout: col=lane&15, row=(lane>>4)*4+r  (row = batch-in-half)
        int col = lane & 15;
        int row = (lane >> 4) * 4;
        #pragma unroll
        for (int r = 0; r < 4; r++)
            zbuf[kh][wm * 16 + row + r][col] = acc0[r];
    }
    __syncthreads();

    if (tid < 128) {     // epilogue: thread (eb, ejl)
        float zi = zbuf[0][eb][ejl]      + zbuf[1][eb][ejl]      + xzi;
        float zf = zbuf[0][eb][4 + ejl]  + zbuf[1][eb][4 + ejl]  + xzf;
        float zg = zbuf[0][eb][8 + ejl]  + zbuf[1][eb][8 + ejl]  + xzg;
        float zo = zbuf[0][eb][12 + ejl] + zbuf[1][eb][12 + ejl] + xzo;
        float ig = sigmf(zi + cv * p[ej]);
        float fg = sigmf(zf + cv * p[1024 + ej]);
        float gg = tanhfast(zg);
        float cn = fg * cv + ig * gg;
        float og = sigmf(zo + cn * p[2048 + ej]);
        float hv = og * tanhfast(cn);
        short hb = f2bf(hv);
        c_st[eb * H_DIM + ej]   = cn;
        h_bf_t[eb * H_DIM + ej] = hb;
        // write h in A-fragment order for next step (same k-slot formula)
        int lane2 = (eb & 15) | (((ej & 31) >> 3) << 4);
        int kt2   = ej >> 5;
        int wm2   = eb >> 4;
        hp_out[(size_t)(((wm2 * 32 + kt2) * 64 + lane2)) * 8 + (ej & 7)] = hb;
    }
}

// ---------------------------------------------------------------------------
extern "C" void kernel_launch(void* const* d_in, const int* in_sizes, int n_in,
                              void* d_out, int out_size, void* d_ws, size_t ws_size,
                              hipStream_t stream)
{
    const float* inp    = (const float*)d_in[0];  // (32,512,256)
    const float* W      = (const float*)d_in[1];  // (256,4096)
    const float* R      = (const float*)d_in[2];  // (512,4096)
    const float* W_proj = (const float*)d_in[3];  // (1024,512)
    const float* p      = (const float*)d_in[4];  // (3072,)
    const float* bvec   = (const float*)d_in[5];  // (4096,)
    const float* lin_w  = (const float*)d_in[6];  // (256,512)
    const float* lin_b  = (const float*)d_in[7];  // (256,)
    float* out = (float*)d_out;
    char* ws = (char*)d_ws;

    float* RRbuf = (float*)(ws + 0);              // 16 MB
    short* RRbp  = (short*)(ws + 16777216);       // 8 MB
    short* Wp_hi = (short*)(ws + 25165824);       // 1 MB
    short* Wp_lo = (short*)(ws + 26214400);
    short* Rt_hi = (short*)(ws + 27262976);       // 4 MB  (R^T planes [4096][512])
    short* Rt_lo = (short*)(ws + 31457280);
    short* Wt_hi = (short*)(ws + 35651584);       // 2 MB  (W^T bf16 [4096][256])
    short* in_hi = (short*)(ws + 39845888);       // 8 MB  (inputs bf16, row-major)
    short* Wpt   = (short*)(ws + 56623104);       // 1 MB  (W_proj^T bf16 [512][1024])
    short* lwb   = (short*)(ws + 57671680);       // 256 KB (lin_w bf16 [256][512])
    float* c_st  = (float*)(ws + 57933824);       // 128 KB
    short* hpk0  = (short*)(ws + 58064896);       // 64 KB
    short* hpk1  = (short*)(ws + 58130432);       // 64 KB
    short* h_bf  = (short*)(ws + 58195968);       // 32 MB  ([512][32][1024] bf16)
    float* xg_c  = (float*)(ws + 91750400);       // 32 MB  (64-step chunk, f32)
    short* hp_bf = (short*)(ws + 125304832);      // 16 MB  ([16384][512] bf16)
    // requires ws_size >= 142,082,048 bytes

    hipMemsetAsync(hpk0, 0, 65536, stream);
    hipMemsetAsync(c_st, 0, B_SZ * H_DIM * sizeof(float), stream);

    // ---- prepack weights/inputs into bf16 planes (hi/lo only where needed) ----
    split_copy<<<(H_DIM * P_DIM + 255) / 256, 256, 0, stream>>>(W_proj, Wp_hi, Wp_lo, H_DIM * P_DIM);
    split_copy<<<(B_SZ * T_SZ * I_DIM + 255) / 256, 256, 0, stream>>>(inp, in_hi, nullptr, B_SZ * T_SZ * I_DIM);
    split_copy<<<(O_DIM * P_DIM + 255) / 256, 256, 0, stream>>>(lin_w, lwb, nullptr, O_DIM * P_DIM);
    transpose_split<<<dim3(G4 / 32, P_DIM / 32), dim3(32, 8), 0, stream>>>(R, Rt_hi, Rt_lo, P_DIM, G4);
    transpose_split<<<dim3(G4 / 32, I_DIM / 32), dim3(32, 8), 0, stream>>>(W, Wt_hi, nullptr, I_DIM, G4);
    transpose_split<<<dim3(P_DIM / 32, H_DIM / 32), dim3(32, 8), 0, stream>>>(W_proj, Wpt, nullptr, H_DIM, P_DIM);

    // ---- RR = W_proj @ R (split-3, ~f32: feeds all 512 steps), pack ----
    gemm_rr<<<dim3(G4 / 128, H_DIM / 128), 256, 0, stream>>>(
        Wp_hi, Wp_lo, Rt_hi, Rt_lo, nullptr, RRbuf, G4, P_DIM, 0);
    pack_rr<<<2048, 256, 0, stream>>>(RRbuf, RRbp);

    // ---- recurrence in 8 chunks of 64 steps (multi-launch, graph-replayed) ----
    for (int chunk = 0; chunk < 8; chunk++) {
        int t0 = chunk * 64;
        gemm_xg<<<dim3(G4 / 128, 2048 / 128), 256, 0, stream>>>(
            in_hi, nullptr, Wt_hi, nullptr, bvec, xg_c, G4, I_DIM, t0);
        for (int tl = 0; tl < 64; tl++) {
            int t = t0 + tl;
            short* hin  = (t & 1) ? hpk1 : hpk0;
            short* hout = (t & 1) ? hpk0 : hpk1;
            lstm_step<<<256, 256, 0, stream>>>(
                xg_c + (size_t)tl * B_SZ * G4, RRbp, hin, hout,
                h_bf + (size_t)t * (B_SZ * H_DIM), c_st, p);
        }
    }

    // ---- hp = h @ W_proj (single-pass bf16, bf16 output) ----
    gemm_proj<<<dim3(P_DIM / 128, 16384 / 128), 256, 0, stream>>>(
        h_bf, nullptr, Wpt, nullptr, nullptr, hp_bf, P_DIM, H_DIM, 0);

    // ---- out = hp @ lin_w^T + lin_b (single-pass bf16, f32 remapped out) ----
    gemm_out<<<dim3(O_DIM / 128, 16384 / 128), 256, 0, stream>>>(
        hp_bf, nullptr, lwb, nullptr, lin_b, out, O_DIM, P_DIM, 0);
}

// Round 12
// 2146.549 us; speedup vs baseline: 1.7247x; 1.1011x over previous
//
#include <hip/hip_runtime.h>
#include <math.h>

// Problem dims
#define B_SZ   32
#define T_SZ   512
#define I_DIM  256
#define H_DIM  1024
#define P_DIM  512
#define G4     4096   // 4*H
#define O_DIM  256

typedef short short8 __attribute__((ext_vector_type(8)));
typedef float f32x4  __attribute__((ext_vector_type(4)));

__device__ __forceinline__ float sigmf(float x) { return 1.0f / (1.0f + __expf(-x)); }
__device__ __forceinline__ float tanhfast(float x) { return 1.0f - 2.0f / (__expf(2.0f * x) + 1.0f); }
__device__ __forceinline__ short f2bf(float f) {
    union { float f; unsigned u; } v; v.f = f;
    unsigned r = (v.u + 0x7FFF + ((v.u >> 16) & 1)) >> 16;
    return (short)r;
}
__device__ __forceinline__ float bf2f(short h) {
    union { unsigned u; float f; } v; v.u = ((unsigned)(unsigned short)h) << 16;
    return v.f;
}

// ---------------------------------------------------------------------------
__global__ void split_copy(const float* __restrict__ in, short* __restrict__ hi,
                           short* __restrict__ lo, int n)
{
    int i = blockIdx.x * 256 + threadIdx.x;
    if (i < n) {
        float v = in[i];
        short h = f2bf(v);
        hi[i] = h;
        if (lo) lo[i] = f2bf(v - bf2f(h));
    }
}

__global__ void transpose_split(const float* __restrict__ in, short* __restrict__ hi,
                                short* __restrict__ lo, int rows, int cols)
{
    __shared__ float t[32][33];
    int c0 = blockIdx.x * 32, r0 = blockIdx.y * 32;
    int x = threadIdx.x, y = threadIdx.y;   // 32 x 8
    #pragma unroll
    for (int i = y; i < 32; i += 8) t[i][x] = in[(size_t)(r0 + i) * cols + c0 + x];
    __syncthreads();
    #pragma unroll
    for (int i = y; i < 32; i += 8) {
        float v = t[x][i];
        short h = f2bf(v);
        size_t o = (size_t)(c0 + i) * rows + r0 + x;
        hi[o] = h;
        if (lo) lo[o] = f2bf(v - bf2f(h));
    }
}

// ---------------------------------------------------------------------------
// MFMA bf16 GEMM tile body (one 128x128 C tile at m0,n0). Same as rounds 4-11.
// ---------------------------------------------------------------------------
template<int SPLIT, int AMODE, int CMODE, int BIAS>
__device__ __forceinline__
void gemm_tile(const short* __restrict__ Ah, const short* __restrict__ Al,
               const short* __restrict__ Bh, const short* __restrict__ Bl,
               const float* __restrict__ bias, void* __restrict__ Cp,
               int N, int K, int t0, int m0, int n0)
{
    __shared__ short As[SPLIT + 1][8192];   // [plane][row*64 + k], 16KB each
    __shared__ short Bs[SPLIT + 1][8192];
    const int tid = threadIdx.x;
    const int l   = tid & 63;
    const int w   = tid >> 6;
    const int wm  = w & 1, wn = w >> 1;

    f32x4 acc[4][4] = {};

    for (int k0 = 0; k0 < K; k0 += 64) {
        __syncthreads();
        #pragma unroll
        for (int q = 0; q < 4; q++) {
            int rg   = q * 4 + w;
            int rr   = (rg << 3) + (l >> 3);
            int slot = (l & 7) ^ (rr & 7);        // pre-swizzled source slot
            int lidx = rg * 512 + l * 8;          // linear LDS dest (shorts)
            size_t aoff, boff;
            int ra = m0 + rr, rb = n0 + rr;
            if constexpr (AMODE == 1)
                aoff = (size_t)((ra & 31) * 512 + t0 + (ra >> 5)) * 256 + k0 + slot * 8;
            else
                aoff = (size_t)ra * K + k0 + slot * 8;
            boff = (size_t)rb * K + k0 + slot * 8;
            __builtin_amdgcn_global_load_lds(Ah + aoff, &As[0][lidx], 16, 0, 0);
            __builtin_amdgcn_global_load_lds(Bh + boff, &Bs[0][lidx], 16, 0, 0);
            if constexpr (SPLIT) {
                __builtin_amdgcn_global_load_lds(Al + aoff, &As[1][lidx], 16, 0, 0);
                __builtin_amdgcn_global_load_lds(Bl + boff, &Bs[1][lidx], 16, 0, 0);
            }
        }
        __syncthreads();

        #pragma unroll
        for (int ks = 0; ks < 2; ks++) {
            const int cb = (((ks * 4) + (l >> 4)) ^ (l & 7)) * 16;  // swizzled col byte
            short8 af[4], bfr[4], afl[4], bfl[4];
            #pragma unroll
            for (int mf = 0; mf < 4; mf++) {
                int mloc = wm * 64 + mf * 16 + (l & 15);
                af[mf] = *(const short8*)((const char*)As[0] + mloc * 128 + cb);
                if constexpr (SPLIT)
                    afl[mf] = *(const short8*)((const char*)As[1] + mloc * 128 + cb);
            }
            #pragma unroll
            for (int nf = 0; nf < 4; nf++) {
                int nloc = wn * 64 + nf * 16 + (l & 15);
                bfr[nf] = *(const short8*)((const char*)Bs[0] + nloc * 128 + cb);
                if constexpr (SPLIT)
                    bfl[nf] = *(const short8*)((const char*)Bs[1] + nloc * 128 + cb);
            }
            #pragma unroll
            for (int mf = 0; mf < 4; mf++)
                #pragma unroll
                for (int nf = 0; nf < 4; nf++)
                    acc[mf][nf] = __builtin_amdgcn_mfma_f32_16x16x32_bf16(
                        af[mf], bfr[nf], acc[mf][nf], 0, 0, 0);
            if constexpr (SPLIT) {
                #pragma unroll
                for (int mf = 0; mf < 4; mf++)
                    #pragma unroll
                    for (int nf = 0; nf < 4; nf++)
                        acc[mf][nf] = __builtin_amdgcn_mfma_f32_16x16x32_bf16(
                            af[mf], bfl[nf], acc[mf][nf], 0, 0, 0);
                #pragma unroll
                for (int mf = 0; mf < 4; mf++)
                    #pragma unroll
                    for (int nf = 0; nf < 4; nf++)
                        acc[mf][nf] = __builtin_amdgcn_mfma_f32_16x16x32_bf16(
                            afl[mf], bfr[nf], acc[mf][nf], 0, 0, 0);
            }
        }
    }

    float bv[4];
    if constexpr (BIAS) {
        #pragma unroll
        for (int nf = 0; nf < 4; nf++)
            bv[nf] = bias[n0 + wn * 64 + nf * 16 + (l & 15)];
    }
    #pragma unroll
    for (int mf = 0; mf < 4; mf++) {
        #pragma unroll
        for (int r = 0; r < 4; r++) {
            int row = m0 + wm * 64 + mf * 16 + (l >> 4) * 4 + r;
            #pragma unroll
            for (int nf = 0; nf < 4; nf++) {
                int col = n0 + wn * 64 + nf * 16 + (l & 15);
                float v = acc[mf][nf][r];
                if constexpr (BIAS) v += bv[nf];
                if constexpr (CMODE == 0)
                    ((float*)Cp)[(size_t)row * N + col] = v;
                else if constexpr (CMODE == 1)
                    ((short*)Cp)[(size_t)row * N + col] = f2bf(v);
                else
                    ((float*)Cp)[(size_t)(row & 31) * (T_SZ * O_DIM)
                                 + (size_t)(row >> 5) * O_DIM + col] = v;
            }
        }
    }
}

// ---- concrete (non-template) kernel entry points ----
// split-3 f32-precision GEMM (used for RR = W_proj@R and PL = W_proj@lin_w^T)
__global__ __launch_bounds__(256)
void gemm_rr(const short* Ah, const short* Al, const short* Bh, const short* Bl,
             const float* bias, void* Cp, int N, int K, int t0)
{ gemm_tile<1, 0, 0, 0>(Ah, Al, Bh, Bl, bias, Cp, N, K, t0, blockIdx.y * 128, blockIdx.x * 128); }

// out = h @ PL + lin_b (single-pass bf16, f32 remapped out)
__global__ __launch_bounds__(256)
void gemm_out(const short* Ah, const short* Al, const short* Bh, const short* Bl,
              const float* bias, void* Cp, int N, int K, int t0)
{ gemm_tile<0, 0, 2, 1>(Ah, Al, Bh, Bl, bias, Cp, N, K, t0, blockIdx.y * 128, blockIdx.x * 128); }

// ---------------------------------------------------------------------------
// Pack RR (f32 [1024 k][4096 gatecol]) -> B-fragments for 256 step-blocks of
// 16 gatecols (4 j x 4 gates): RRbp[blk 256][kt 32][lane 64][i 8];
// nl=lane&15 -> g=nl>>2, jl=nl&3, col = g*1024 + blk*4 + jl;
// k = kt*32 + (lane>>4)*8 + i  (same k-slot formula as hpk/inp_pk A-packs,
// so any k-permutation ambiguity cancels in the dot product).
// ---------------------------------------------------------------------------
__global__ __launch_bounds__(256)
void pack_rr(const float* __restrict__ RRf, short* __restrict__ RRbp)
{
    int idx = blockIdx.x * 256 + threadIdx.x;     // short8 slot, 0..524287
    int lane = idx & 63;
    int kt   = (idx >> 6) & 31;
    int blk  = idx >> 11;
    int nl = lane & 15;
    int g = nl >> 2, jl = nl & 3;
    int col = g * 1024 + blk * 4 + jl;
    int kbase = kt * 32 + (lane >> 4) * 8;
    short8 v;
    #pragma unroll
    for (int i = 0; i < 8; i++)
        v[i] = f2bf(RRf[(size_t)(kbase + i) * G4 + col]);
    ((short8*)RRbp)[idx] = v;
}

// Pack W (f32 [256 k][4096 gatecol]) -> Wbp[blk 256][kt 8][lane 64][i 8]
__global__ __launch_bounds__(256)
void pack_w(const float* __restrict__ Wf, short* __restrict__ Wbp)
{
    int idx = blockIdx.x * 256 + threadIdx.x;     // short8 slot, 0..131071
    int lane = idx & 63;
    int kt   = (idx >> 6) & 7;
    int blk  = idx >> 9;
    int nl = lane & 15;
    int g = nl >> 2, jl = nl & 3;
    int col = g * 1024 + blk * 4 + jl;
    int kbase = kt * 32 + (lane >> 4) * 8;
    short8 v;
    #pragma unroll
    for (int i = 0; i < 8; i++)
        v[i] = f2bf(Wf[(size_t)(kbase + i) * G4 + col]);
    ((short8*)Wbp)[idx] = v;
}

// Pack inputs (f32 (32,512,256)) -> inp_pk[t 512][wm 2][kt 8][lane 64][i 8]
// bf16 A-fragments: b = wm*16 + (lane&15), k = kt*32 + (lane>>4)*8 + i.
__global__ __launch_bounds__(256)
void pack_x(const float* __restrict__ inp, short* __restrict__ xpk)
{
    int idx = blockIdx.x * 256 + threadIdx.x;     // short8 slot, 0..524287
    int lane = idx & 63;
    int kt   = (idx >> 6) & 7;
    int wm   = (idx >> 9) & 1;
    int t    = idx >> 10;
    int b = wm * 16 + (lane & 15);
    int kbase = kt * 32 + (lane >> 4) * 8;
    const float* src = inp + ((size_t)b * T_SZ + t) * I_DIM + kbase;
    short8 v;
    #pragma unroll
    for (int i = 0; i < 8; i++) v[i] = f2bf(src[i]);
    ((short8*)xpk)[idx] = v;
}

// ---------------------------------------------------------------------------
// One LSTM step via MFMA, xg FUSED. Grid: 256 blocks (4 j-cols), 256 threads.
// 4 waves = (wm batch-half) x (kh K-half); per wave 16 h-MFMA (K=1024/2)
// + 4 x-MFMA (K=256/2). Partials reduced via zbuf; epilogue adds bias and
// applies gates; c in global (L2-hot), bias/c prefetched at entry.
// ---------------------------------------------------------------------------
__global__ __launch_bounds__(256)
void lstm_step(const short* __restrict__ xpk_t,
               const short* __restrict__ Wbp,
               const short* __restrict__ RRbp,
               const short* __restrict__ hp_in,
               short* __restrict__ hp_out,
               short* __restrict__ h_bf_t,
               float* __restrict__ c_st,
               const float* __restrict__ p,
               const float* __restrict__ bvec)
{
    __shared__ float zbuf[2][32][17];
    const int tid  = threadIdx.x;
    const int bid  = blockIdx.x;          // j0 = bid*4
    const int lane = tid & 63;
    const int w    = tid >> 6;
    const int wm   = w & 1;               // batch half
    const int kh   = w >> 1;              // K half

    // ---- epilogue-role prefetch (bias + c), issued before the MFMA chain ----
    const int eb = tid >> 2, ejl = tid & 3;       // valid when tid < 128
    const int ej = bid * 4 + ejl;
    float bzi = 0.f, bzf = 0.f, bzg = 0.f, bzo = 0.f, cv = 0.f;
    if (tid < 128) {
        bzi = bvec[ej]; bzf = bvec[1024 + ej];
        bzg = bvec[2048 + ej]; bzo = bvec[3072 + ej];
        cv = c_st[eb * H_DIM + ej];
    }

    const short8* Ap  = (const short8*)hp_in + (size_t)(wm * 32 + kh * 16) * 64 + lane;
    const short8* Bp  = (const short8*)RRbp + (size_t)(bid * 32 + kh * 16) * 64 + lane;
    const short8* Apx = (const short8*)xpk_t + (size_t)(wm * 8 + kh * 4) * 64 + lane;
    const short8* Bpx = (const short8*)Wbp + (size_t)(bid * 8 + kh * 4) * 64 + lane;

    f32x4 acc0 = {0.f, 0.f, 0.f, 0.f};
    f32x4 acc1 = {0.f, 0.f, 0.f, 0.f};
    // x-part (operands L2-hot; 2+2 MFMA across the two chains)
    #pragma unroll
    for (int i = 0; i < 2; i++) {
        short8 a = Apx[(size_t)i * 64];
        short8 b = Bpx[(size_t)i * 64];
        acc0 = __builtin_amdgcn_mfma_f32_16x16x32_bf16(a, b, acc0, 0, 0, 0);
    }
    #pragma unroll
    for (int i = 2; i < 4; i++) {
        short8 a = Apx[(size_t)i * 64];
        short8 b = Bpx[(size_t)i * 64];
        acc1 = __builtin_amdgcn_mfma_f32_16x16x32_bf16(a, b, acc1, 0, 0, 0);
    }
    // h-part
    #pragma unroll
    for (int i = 0; i < 8; i++) {
        short8 a = Ap[(size_t)i * 64];
        short8 b = Bp[(size_t)i * 64];
        acc0 = __builtin_amdgcn_mfma_f32_16x16x32_bf16(a, b, acc0, 0, 0, 0);
    }
    #pragma unroll
    for (int i = 8; i < 16; i++) {
        short8 a = Ap[(size_t)i * 64];
        short8 b = Bp[(size_t)i * 64];
        acc1 = __builtin_amdgcn_mfma_f32_16x16x32_bf16(a, b, acc1, 0, 0, 0);
    }
    acc0[0] += acc1[0]; acc0[1] += acc1[1]; acc0[2] += acc1[2]; acc0[3] += acc1[3];

    {   // C/D layout: col=lane&15, row=(lane>>4)*4+r  (row = batch-in-half)
        int col = lane & 15;
        int row = (lane >> 4) * 4;
        #pragma unroll
        for (int r = 0; r < 4; r++)
            zbuf[kh][wm * 16 + row + r][col] = acc0[r];
    }
    __syncthreads();

    if (tid < 128) {     // epilogue: thread (eb, ejl)
        float zi = zbuf[0][eb][ejl]      + zbuf[1][eb][ejl]      + bzi;
        float zf = zbuf[0][eb][4 + ejl]  + zbuf[1][eb][4 + ejl]  + bzf;
        float zg = zbuf[0][eb][8 + ejl]  + zbuf[1][eb][8 + ejl]  + bzg;
        float zo = zbuf[0][eb][12 + ejl] + zbuf[1][eb][12 + ejl] + bzo;
        float ig = sigmf(zi + cv * p[ej]);
        float fg = sigmf(zf + cv * p[1024 + ej]);
        float gg = tanhfast(zg);
        float cn = fg * cv + ig * gg;
        float og = sigmf(zo + cn * p[2048 + ej]);
        float hv = og * tanhfast(cn);
        short hb = f2bf(hv);
        c_st[eb * H_DIM + ej]   = cn;
        h_bf_t[eb * H_DIM + ej] = hb;
        // write h in A-fragment order for next step (same k-slot formula)
        int lane2 = (eb & 15) | (((ej & 31) >> 3) << 4);
        int kt2   = ej >> 5;
        int wm2   = eb >> 4;
        hp_out[(size_t)(((wm2 * 32 + kt2) * 64 + lane2)) * 8 + (ej & 7)] = hb;
    }
}

// ---------------------------------------------------------------------------
extern "C" void kernel_launch(void* const* d_in, const int* in_sizes, int n_in,
                              void* d_out, int out_size, void* d_ws, size_t ws_size,
                              hipStream_t stream)
{
    const float* inp    = (const float*)d_in[0];  // (32,512,256)
    const float* W      = (const float*)d_in[1];  // (256,4096)
    const float* R      = (const float*)d_in[2];  // (512,4096)
    const float* W_proj = (const float*)d_in[3];  // (1024,512)
    const float* p      = (const float*)d_in[4];  // (3072,)
    const float* bvec   = (const float*)d_in[5];  // (4096,)
    const float* lin_w  = (const float*)d_in[6];  // (256,512)
    const float* lin_b  = (const float*)d_in[7];  // (256,)
    float* out = (float*)d_out;
    char* ws = (char*)d_ws;

    float* RRbuf = (float*)(ws + 0);              // 16 MB (dead after pack_rr)
    short* RRbp  = (short*)(ws + 16777216);       // 8 MB
    short* Wp_hi = (short*)(ws + 25165824);       // 1 MB
    short* Wp_lo = (short*)(ws + 26214400);       // 1 MB
    short* Rt_hi = (short*)(ws + 27262976);       // 4 MB  (R^T planes [4096][512])
    short* Rt_lo = (short*)(ws + 31457280);       // 4 MB
    short* lwb_h = (short*)(ws + 35651584);       // 256 KB (lin_w [256][512] hi)
    short* lwb_l = (short*)(ws + 35913728);       // 256 KB (lo)
    short* Wbp   = (short*)(ws + 36175872);       // 2 MB  (W B-fragments)
    short* xpk   = (short*)(ws + 38273024);       // 8 MB  (inputs A-fragments)
    float* PLbuf = (float*)(ws + 46661632);       // 1 MB  (PL = W_proj@lin_w^T, f32)
    short* PLt   = (short*)(ws + 47710208);       // 512 KB (PL^T bf16 [256][1024])
    float* c_st  = (float*)(ws + 48234496);       // 128 KB
    short* hpk0  = (short*)(ws + 48365568);       // 64 KB
    short* hpk1  = (short*)(ws + 48431104);       // 64 KB
    short* h_bf  = (short*)(ws + 48496640);       // 32 MB ([512][32][1024] bf16)
    // requires ws_size >= 82,051,072 bytes

    hipMemsetAsync(hpk0, 0, 65536, stream);
    hipMemsetAsync(c_st, 0, B_SZ * H_DIM * sizeof(float), stream);

    // ---- prepack ----
    pack_x<<<2048, 256, 0, stream>>>(inp, xpk);
    pack_w<<<512, 256, 0, stream>>>(W, Wbp);
    split_copy<<<(H_DIM * P_DIM + 255) / 256, 256, 0, stream>>>(W_proj, Wp_hi, Wp_lo, H_DIM * P_DIM);
    split_copy<<<(O_DIM * P_DIM + 255) / 256, 256, 0, stream>>>(lin_w, lwb_h, lwb_l, O_DIM * P_DIM);
    transpose_split<<<dim3(G4 / 32, P_DIM / 32), dim3(32, 8), 0, stream>>>(R, Rt_hi, Rt_lo, P_DIM, G4);

    // ---- RR = W_proj @ R (split-3, ~f32: feeds all 512 steps), pack ----
    gemm_rr<<<dim3(G4 / 128, H_DIM / 128), 256, 0, stream>>>(
        Wp_hi, Wp_lo, Rt_hi, Rt_lo, nullptr, RRbuf, G4, P_DIM, 0);
    pack_rr<<<2048, 256, 0, stream>>>(RRbuf, RRbp);

    // ---- PL = W_proj @ lin_w^T (split-3 f32), then transpose to bf16 B^T ----
    gemm_rr<<<dim3(O_DIM / 128, H_DIM / 128), 256, 0, stream>>>(
        Wp_hi, Wp_lo, lwb_h, lwb_l, nullptr, PLbuf, O_DIM, P_DIM, 0);
    transpose_split<<<dim3(O_DIM / 32, H_DIM / 32), dim3(32, 8), 0, stream>>>(
        PLbuf, PLt, nullptr, H_DIM, O_DIM);

    // ---- recurrence: 512 dependent step launches (xg fused in-kernel) ----
    for (int t = 0; t < T_SZ; t++) {
        short* hin  = (t & 1) ? hpk1 : hpk0;
        short* hout = (t & 1) ? hpk0 : hpk1;
        lstm_step<<<256, 256, 0, stream>>>(
            xpk + (size_t)t * (2 * 8 * 64 * 8), Wbp, RRbp, hin, hout,
            h_bf + (size_t)t * (B_SZ * H_DIM), c_st, p, bvec);
    }

    // ---- out = h @ PL + lin_b (single-pass bf16, f32 remapped out) ----
    gemm_out<<<dim3(O_DIM / 128, 16384 / 128), 256, 0, stream>>>(
        h_bf, nullptr, PLt, nullptr, lin_b, out, O_DIM, H_DIM, 0);
}

// Round 13
// 2105.190 us; speedup vs baseline: 1.7586x; 1.0196x over previous
//
#include <hip/hip_runtime.h>
#include <math.h>

// Problem dims
#define B_SZ   32
#define T_SZ   512
#define I_DIM  256
#define H_DIM  1024
#define P_DIM  512
#define G4     4096   // 4*H
#define O_DIM  256

typedef short short8 __attribute__((ext_vector_type(8)));
typedef float f32x4  __attribute__((ext_vector_type(4)));

__device__ __forceinline__ float sigmf(float x) { return 1.0f / (1.0f + __expf(-x)); }
__device__ __forceinline__ float tanhfast(float x) { return 1.0f - 2.0f / (__expf(2.0f * x) + 1.0f); }
__device__ __forceinline__ short f2bf(float f) {
    union { float f; unsigned u; } v; v.f = f;
    unsigned r = (v.u + 0x7FFF + ((v.u >> 16) & 1)) >> 16;
    return (short)r;
}
__device__ __forceinline__ float bf2f(short h) {
    union { unsigned u; float f; } v; v.u = ((unsigned)(unsigned short)h) << 16;
    return v.f;
}

// ---------------------------------------------------------------------------
// MFMA bf16 GEMM tile body (one 128x128 C tile at m0,n0). Same as rounds 4-12.
// ---------------------------------------------------------------------------
template<int SPLIT, int CMODE, int BIAS>
__device__ __forceinline__
void gemm_tile(const short* __restrict__ Ah, const short* __restrict__ Al,
               const short* __restrict__ Bh, const short* __restrict__ Bl,
               const float* __restrict__ bias, void* __restrict__ Cp,
               int N, int K, int m0, int n0)
{
    __shared__ short As[SPLIT + 1][8192];   // [plane][row*64 + k], 16KB each
    __shared__ short Bs[SPLIT + 1][8192];
    const int tid = threadIdx.x;
    const int l   = tid & 63;
    const int w   = tid >> 6;
    const int wm  = w & 1, wn = w >> 1;

    f32x4 acc[4][4] = {};

    for (int k0 = 0; k0 < K; k0 += 64) {
        __syncthreads();
        #pragma unroll
        for (int q = 0; q < 4; q++) {
            int rg   = q * 4 + w;
            int rr   = (rg << 3) + (l >> 3);
            int slot = (l & 7) ^ (rr & 7);        // pre-swizzled source slot
            int lidx = rg * 512 + l * 8;          // linear LDS dest (shorts)
            size_t aoff = (size_t)(m0 + rr) * K + k0 + slot * 8;
            size_t boff = (size_t)(n0 + rr) * K + k0 + slot * 8;
            __builtin_amdgcn_global_load_lds(Ah + aoff, &As[0][lidx], 16, 0, 0);
            __builtin_amdgcn_global_load_lds(Bh + boff, &Bs[0][lidx], 16, 0, 0);
            if constexpr (SPLIT) {
                __builtin_amdgcn_global_load_lds(Al + aoff, &As[1][lidx], 16, 0, 0);
                __builtin_amdgcn_global_load_lds(Bl + boff, &Bs[1][lidx], 16, 0, 0);
            }
        }
        __syncthreads();

        #pragma unroll
        for (int ks = 0; ks < 2; ks++) {
            const int cb = (((ks * 4) + (l >> 4)) ^ (l & 7)) * 16;  // swizzled col byte
            short8 af[4], bfr[4], afl[4], bfl[4];
            #pragma unroll
            for (int mf = 0; mf < 4; mf++) {
                int mloc = wm * 64 + mf * 16 + (l & 15);
                af[mf] = *(const short8*)((const char*)As[0] + mloc * 128 + cb);
                if constexpr (SPLIT)
                    afl[mf] = *(const short8*)((const char*)As[1] + mloc * 128 + cb);
            }
            #pragma unroll
            for (int nf = 0; nf < 4; nf++) {
                int nloc = wn * 64 + nf * 16 + (l & 15);
                bfr[nf] = *(const short8*)((const char*)Bs[0] + nloc * 128 + cb);
                if constexpr (SPLIT)
                    bfl[nf] = *(const short8*)((const char*)Bs[1] + nloc * 128 + cb);
            }
            #pragma unroll
            for (int mf = 0; mf < 4; mf++)
                #pragma unroll
                for (int nf = 0; nf < 4; nf++)
                    acc[mf][nf] = __builtin_amdgcn_mfma_f32_16x16x32_bf16(
                        af[mf], bfr[nf], acc[mf][nf], 0, 0, 0);
            if constexpr (SPLIT) {
                #pragma unroll
                for (int mf = 0; mf < 4; mf++)
                    #pragma unroll
                    for (int nf = 0; nf < 4; nf++)
                        acc[mf][nf] = __builtin_amdgcn_mfma_f32_16x16x32_bf16(
                            af[mf], bfl[nf], acc[mf][nf], 0, 0, 0);
                #pragma unroll
                for (int mf = 0; mf < 4; mf++)
                    #pragma unroll
                    for (int nf = 0; nf < 4; nf++)
                        acc[mf][nf] = __builtin_amdgcn_mfma_f32_16x16x32_bf16(
                            afl[mf], bfr[nf], acc[mf][nf], 0, 0, 0);
            }
        }
    }

    float bv[4];
    if constexpr (BIAS) {
        #pragma unroll
        for (int nf = 0; nf < 4; nf++)
            bv[nf] = bias[n0 + wn * 64 + nf * 16 + (l & 15)];
    }
    #pragma unroll
    for (int mf = 0; mf < 4; mf++) {
        #pragma unroll
        for (int r = 0; r < 4; r++) {
            int row = m0 + wm * 64 + mf * 16 + (l >> 4) * 4 + r;
            #pragma unroll
            for (int nf = 0; nf < 4; nf++) {
                int col = n0 + wn * 64 + nf * 16 + (l & 15);
                float v = acc[mf][nf][r];
                if constexpr (BIAS) v += bv[nf];
                if constexpr (CMODE == 0)
                    ((float*)Cp)[(size_t)row * N + col] = v;
                else
                    ((float*)Cp)[(size_t)(row & 31) * (T_SZ * O_DIM)
                                 + (size_t)(row >> 5) * O_DIM + col] = v;
            }
        }
    }
}

// ---------------------------------------------------------------------------
// prep_all: fused prepack (block-range dispatch), 7168 blocks x 256 threads.
//  [0,2048)    pack_x : inputs f32 -> xpk A-fragments
//  [2048,2560) pack_w : W f32 -> Wbp B-fragments
//  [2560,4608) split  W_proj -> Wp_hi/Wp_lo
//  [4608,5120) split  lin_w  -> lwb_h/lwb_l
//  [5120,7168) transpose+split R -> Rt_hi/Rt_lo  [4096][512]
// ---------------------------------------------------------------------------
__global__ __launch_bounds__(256)
void prep_all(const float* __restrict__ inp, const float* __restrict__ W,
              const float* __restrict__ W_proj, const float* __restrict__ lin_w,
              const float* __restrict__ R,
              short* __restrict__ xpk, short* __restrict__ Wbp,
              short* __restrict__ Wp_hi, short* __restrict__ Wp_lo,
              short* __restrict__ lwb_h, short* __restrict__ lwb_l,
              short* __restrict__ Rt_hi, short* __restrict__ Rt_lo)
{
    __shared__ float t[32][33];
    const int blk = blockIdx.x, tid = threadIdx.x;

    if (blk < 2048) {                       // ---- pack_x ----
        int idx = blk * 256 + tid;
        int lane = idx & 63;
        int kt   = (idx >> 6) & 7;
        int wm   = (idx >> 9) & 1;
        int tt   = idx >> 10;
        int b = wm * 16 + (lane & 15);
        int kbase = kt * 32 + (lane >> 4) * 8;
        const float* src = inp + ((size_t)b * T_SZ + tt) * I_DIM + kbase;
        short8 v;
        #pragma unroll
        for (int i = 0; i < 8; i++) v[i] = f2bf(src[i]);
        ((short8*)xpk)[idx] = v;
    } else if (blk < 2560) {                // ---- pack_w ----
        int idx = (blk - 2048) * 256 + tid;
        int lane = idx & 63;
        int kt   = (idx >> 6) & 7;
        int jblk = idx >> 9;
        int nl = lane & 15;
        int g = nl >> 2, jl = nl & 3;
        int col = g * 1024 + jblk * 4 + jl;
        int kbase = kt * 32 + (lane >> 4) * 8;
        short8 v;
        #pragma unroll
        for (int i = 0; i < 8; i++)
            v[i] = f2bf(W[(size_t)(kbase + i) * G4 + col]);
        ((short8*)Wbp)[idx] = v;
    } else if (blk < 4608) {                // ---- split W_proj ----
        int i = (blk - 2560) * 256 + tid;
        float v = W_proj[i];
        short h = f2bf(v);
        Wp_hi[i] = h;
        Wp_lo[i] = f2bf(v - bf2f(h));
    } else if (blk < 5120) {                // ---- split lin_w ----
        int i = (blk - 4608) * 256 + tid;
        float v = lin_w[i];
        short h = f2bf(v);
        lwb_h[i] = h;
        lwb_l[i] = f2bf(v - bf2f(h));
    } else {                                // ---- transpose+split R ----
        int b2 = blk - 5120;                // grid (128 x, 16 y)
        int c0 = (b2 & 127) * 32, r0 = (b2 >> 7) * 32;
        int x = tid & 31, y = tid >> 5;     // 32 x 8
        #pragma unroll
        for (int i = y; i < 32; i += 8) t[i][x] = R[(size_t)(r0 + i) * G4 + c0 + x];
        __syncthreads();
        #pragma unroll
        for (int i = y; i < 32; i += 8) {
            float v = t[x][i];
            short h = f2bf(v);
            size_t o = (size_t)(c0 + i) * P_DIM + r0 + x;
            Rt_hi[o] = h;
            Rt_lo[o] = f2bf(v - bf2f(h));
        }
    }
}

// ---------------------------------------------------------------------------
// gemm2: RR = W_proj@R (256 blocks) + PL = W_proj@lin_w^T (16 blocks),
// both split-3 ~f32 precision. 272 blocks total.
// ---------------------------------------------------------------------------
__global__ __launch_bounds__(256)
void gemm2(const short* Wp_hi, const short* Wp_lo,
           const short* Rt_hi, const short* Rt_lo,
           const short* lwb_h, const short* lwb_l,
           float* RRbuf, float* PLbuf)
{
    int blk = blockIdx.x;
    if (blk < 256) {        // RR: grid (32 x, 8 y), N=4096, K=512
        int m0 = (blk >> 5) * 128, n0 = (blk & 31) * 128;
        gemm_tile<1, 0, 0>(Wp_hi, Wp_lo, Rt_hi, Rt_lo, nullptr, RRbuf,
                           G4, P_DIM, m0, n0);
    } else {                // PL: grid (2 x, 8 y), N=256, K=512
        int b2 = blk - 256;
        int m0 = (b2 >> 1) * 128, n0 = (b2 & 1) * 128;
        gemm_tile<1, 0, 0>(Wp_hi, Wp_lo, lwb_h, lwb_l, nullptr, PLbuf,
                           O_DIM, P_DIM, m0, n0);
    }
}

// ---------------------------------------------------------------------------
// pack2: pack_rr (2048) + transpose PL->PLt bf16 (256) + zero hpk0 (16)
// + zero c_st (32). 2352 blocks. Replaces 2 hipMemsetAsync nodes too.
// ---------------------------------------------------------------------------
__global__ __launch_bounds__(256)
void pack2(const float* __restrict__ RRf, short* __restrict__ RRbp,
           const float* __restrict__ PLbuf, short* __restrict__ PLt,
           float* __restrict__ hpk0z, float* __restrict__ c_st)
{
    __shared__ float t[32][33];
    const int blk = blockIdx.x, tid = threadIdx.x;

    if (blk < 2048) {                       // ---- pack_rr ----
        int idx = blk * 256 + tid;
        int lane = idx & 63;
        int kt   = (idx >> 6) & 31;
        int jblk = idx >> 11;
        int nl = lane & 15;
        int g = nl >> 2, jl = nl & 3;
        int col = g * 1024 + jblk * 4 + jl;
        int kbase = kt * 32 + (lane >> 4) * 8;
        short8 v;
        #pragma unroll
        for (int i = 0; i < 8; i++)
            v[i] = f2bf(RRf[(size_t)(kbase + i) * G4 + col]);
        ((short8*)RRbp)[idx] = v;
    } else if (blk < 2304) {                // ---- transpose PL [1024][256] -> PLt [256][1024] ----
        int b2 = blk - 2048;                // grid (8 x, 32 y)
        int c0 = (b2 & 7) * 32, r0 = (b2 >> 3) * 32;
        int x = tid & 31, y = tid >> 5;
        #pragma unroll
        for (int i = y; i < 32; i += 8) t[i][x] = PLbuf[(size_t)(r0 + i) * O_DIM + c0 + x];
        __syncthreads();
        #pragma unroll
        for (int i = y; i < 32; i += 8)
            PLt[(size_t)(c0 + i) * H_DIM + r0 + x] = f2bf(t[x][i]);
    } else if (blk < 2320) {                // ---- zero hpk0 (64 KB) ----
        int idx = (blk - 2304) * 256 + tid;
        ((float4*)hpk0z)[idx] = make_float4(0.f, 0.f, 0.f, 0.f);
    } else {                                // ---- zero c_st (128 KB) ----
        int idx = (blk - 2320) * 256 + tid;
        ((float4*)c_st)[idx] = make_float4(0.f, 0.f, 0.f, 0.f);
    }
}

// ---------------------------------------------------------------------------
// out = h @ PL + lin_b (single-pass bf16, f32 remapped out)
// ---------------------------------------------------------------------------
__global__ __launch_bounds__(256)
void gemm_out(const short* Ah, const short* Bh, const float* bias, void* Cp)
{
    gemm_tile<0, 2, 1>(Ah, nullptr, Bh, nullptr, bias, Cp,
                       O_DIM, H_DIM, blockIdx.y * 128, blockIdx.x * 128);
}

// ---------------------------------------------------------------------------
// One LSTM step via MFMA, xg fused. BYTE-IDENTICAL logic to round 12.
// Grid: 256 blocks (4 j-cols), 256 threads; 4 waves = (wm bh) x (kh Kh);
// per wave 16 h-MFMA + 4 x-MFMA; zbuf reduce; 128-thread epilogue.
// ---------------------------------------------------------------------------
__global__ __launch_bounds__(256)
void lstm_step(const short* __restrict__ xpk_t,
               const short* __restrict__ Wbp,
               const short* __restrict__ RRbp,
               const short* __restrict__ hp_in,
               short* __restrict__ hp_out,
               short* __restrict__ h_bf_t,
               float* __restrict__ c_st,
               const float* __restrict__ p,
               const float* __restrict__ bvec)
{
    __shared__ float zbuf[2][32][17];
    const int tid  = threadIdx.x;
    const int bid  = blockIdx.x;          // j0 = bid*4
    const int lane = tid & 63;
    const int w    = tid >> 6;
    const int wm   = w & 1;               // batch half
    const int kh   = w >> 1;              // K half

    const int eb = tid >> 2, ejl = tid & 3;       // valid when tid < 128
    const int ej = bid * 4 + ejl;
    float bzi = 0.f, bzf = 0.f, bzg = 0.f, bzo = 0.f, cv = 0.f;
    if (tid < 128) {
        bzi = bvec[ej]; bzf = bvec[1024 + ej];
        bzg = bvec[2048 + ej]; bzo = bvec[3072 + ej];
        cv = c_st[eb * H_DIM + ej];
    }

    const short8* Ap  = (const short8*)hp_in + (size_t)(wm * 32 + kh * 16) * 64 + lane;
    const short8* Bp  = (const short8*)RRbp + (size_t)(bid * 32 + kh * 16) * 64 + lane;
    const short8* Apx = (const short8*)xpk_t + (size_t)(wm * 8 + kh * 4) * 64 + lane;
    const short8* Bpx = (const short8*)Wbp + (size_t)(bid * 8 + kh * 4) * 64 + lane;

    f32x4 acc0 = {0.f, 0.f, 0.f, 0.f};
    f32x4 acc1 = {0.f, 0.f, 0.f, 0.f};
    #pragma unroll
    for (int i = 0; i < 2; i++) {
        short8 a = Apx[(size_t)i * 64];
        short8 b = Bpx[(size_t)i * 64];
        acc0 = __builtin_amdgcn_mfma_f32_16x16x32_bf16(a, b, acc0, 0, 0, 0);
    }
    #pragma unroll
    for (int i = 2; i < 4; i++) {
        short8 a = Apx[(size_t)i * 64];
        short8 b = Bpx[(size_t)i * 64];
        acc1 = __builtin_amdgcn_mfma_f32_16x16x32_bf16(a, b, acc1, 0, 0, 0);
    }
    #pragma unroll
    for (int i = 0; i < 8; i++) {
        short8 a = Ap[(size_t)i * 64];
        short8 b = Bp[(size_t)i * 64];
        acc0 = __builtin_amdgcn_mfma_f32_16x16x32_bf16(a, b, acc0, 0, 0, 0);
    }
    #pragma unroll
    for (int i = 8; i < 16; i++) {
        short8 a = Ap[(size_t)i * 64];
        short8 b = Bp[(size_t)i * 64];
        acc1 = __builtin_amdgcn_mfma_f32_16x16x32_bf16(a, b, acc1, 0, 0, 0);
    }
    acc0[0] += acc1[0]; acc0[1] += acc1[1]; acc0[2] += acc1[2]; acc0[3] += acc1[3];

    {   // C/D layout: col=lane&15, row=(lane>>4)*4+r  (row = batch-in-half)
        int col = lane & 15;
        int row = (lane >> 4) * 4;
        #pragma unroll
        for (int r = 0; r < 4; r++)
            zbuf[kh][wm * 16 + row + r][col] = acc0[r];
    }
    __syncthreads();

    if (tid < 128) {     // epilogue: thread (eb, ejl)
        float zi = zbuf[0][eb][ejl]      + zbuf[1][eb][ejl]      + bzi;
        float zf = zbuf[0][eb][4 + ejl]  + zbuf[1][eb][4 + ejl]  + bzf;
        float zg = zbuf[0][eb][8 + ejl]  + zbuf[1][eb][8 + ejl]  + bzg;
        float zo = zbuf[0][eb][12 + ejl] + zbuf[1][eb][12 + ejl] + bzo;
        float ig = sigmf(zi + cv * p[ej]);
        float fg = sigmf(zf + cv * p[1024 + ej]);
        float gg = tanhfast(zg);
        float cn = fg * cv + ig * gg;
        float og = sigmf(zo + cn * p[2048 + ej]);
        float hv = og * tanhfast(cn);
        short hb = f2bf(hv);
        c_st[eb * H_DIM + ej]   = cn;
        h_bf_t[eb * H_DIM + ej] = hb;
        int lane2 = (eb & 15) | (((ej & 31) >> 3) << 4);
        int kt2   = ej >> 5;
        int wm2   = eb >> 4;
        hp_out[(size_t)(((wm2 * 32 + kt2) * 64 + lane2)) * 8 + (ej & 7)] = hb;
    }
}

// ---------------------------------------------------------------------------
extern "C" void kernel_launch(void* const* d_in, const int* in_sizes, int n_in,
                              void* d_out, int out_size, void* d_ws, size_t ws_size,
                              hipStream_t stream)
{
    const float* inp    = (const float*)d_in[0];  // (32,512,256)
    const float* W      = (const float*)d_in[1];  // (256,4096)
    const float* R      = (const float*)d_in[2];  // (512,4096)
    const float* W_proj = (const float*)d_in[3];  // (1024,512)
    const float* p      = (const float*)d_in[4];  // (3072,)
    const float* bvec   = (const float*)d_in[5];  // (4096,)
    const float* lin_w  = (const float*)d_in[6];  // (256,512)
    const float* lin_b  = (const float*)d_in[7];  // (256,)
    float* out = (float*)d_out;
    char* ws = (char*)d_ws;

    float* RRbuf = (float*)(ws + 0);              // 16 MB (dead after pack2)
    short* RRbp  = (short*)(ws + 16777216);       // 8 MB
    short* Wp_hi = (short*)(ws + 25165824);       // 1 MB
    short* Wp_lo = (short*)(ws + 26214400);       // 1 MB
    short* Rt_hi = (short*)(ws + 27262976);       // 4 MB  (R^T planes [4096][512])
    short* Rt_lo = (short*)(ws + 31457280);       // 4 MB
    short* lwb_h = (short*)(ws + 35651584);       // 256 KB
    short* lwb_l = (short*)(ws + 35913728);       // 256 KB
    short* Wbp   = (short*)(ws + 36175872);       // 2 MB  (W B-fragments)
    short* xpk   = (short*)(ws + 38273024);       // 8 MB  (inputs A-fragments)
    float* PLbuf = (float*)(ws + 46661632);       // 1 MB  (PL = W_proj@lin_w^T)
    short* PLt   = (short*)(ws + 47710208);       // 512 KB (PL^T bf16 [256][1024])
    float* c_st  = (float*)(ws + 48234496);       // 128 KB
    short* hpk0  = (short*)(ws + 48365568);       // 64 KB
    short* hpk1  = (short*)(ws + 48431104);       // 64 KB
    short* h_bf  = (short*)(ws + 48496640);       // 32 MB ([512][32][1024] bf16)
    // requires ws_size >= 82,051,072 bytes

    // ---- setup: 3 fused graph nodes ----
    prep_all<<<7168, 256, 0, stream>>>(inp, W, W_proj, lin_w, R,
                                       xpk, Wbp, Wp_hi, Wp_lo,
                                       lwb_h, lwb_l, Rt_hi, Rt_lo);
    gemm2<<<272, 256, 0, stream>>>(Wp_hi, Wp_lo, Rt_hi, Rt_lo,
                                   lwb_h, lwb_l, RRbuf, PLbuf);
    pack2<<<2352, 256, 0, stream>>>(RRbuf, RRbp, PLbuf, PLt,
                                    (float*)hpk0, c_st);

    // ---- recurrence: 512 dependent step launches (xg fused in-kernel) ----
    for (int t = 0; t < T_SZ; t++) {
        short* hin  = (t & 1) ? hpk1 : hpk0;
        short* hout = (t & 1) ? hpk0 : hpk1;
        lstm_step<<<256, 256, 0, stream>>>(
            xpk + (size_t)t * (2 * 8 * 64 * 8), Wbp, RRbp, hin, hout,
            h_bf + (size_t)t * (B_SZ * H_DIM), c_st, p, bvec);
    }

    // ---- out = h @ PL + lin_b (single-pass bf16, f32 remapped out) ----
    gemm_out<<<dim3(O_DIM / 128, 16384 / 128), 256, 0, stream>>>(
        h_bf, PLt, lin_b, out);
}